// Round 20
// baseline (124.988 us; speedup 1.0000x reference)
//
#include <hip/hip_runtime.h>
#include <math.h>

// GraphSAGE (mean) + GCN + softmax. Activations AND weights RNE-bf16
// (single-term), f32 accumulate via MFMA (operand-swapped: A=weights,
// B=activations). hw stored pre-scaled by dinv. Fixed-stride adjacency
// (24 slots/node) + overflow list. Merged dispatch: x->bf16 convert blocks
// FIRST (BW-bound, saturates device), 4-range edge-fill backfills (latency
// hides under convert). Gathers: col-prefetch + shfl, 4-deep pipeline.
// sage_gemm: T14 async-STAGE split.
// N=100000, E=625000, D_IN=D_H=128, D_OUT=64 (derived from in_sizes).

#define DIN 128
#define DH  128
#define DOUT 64
#define NT  32      // nodes per GEMM tile
#define FIX 24      // fixed adjacency slots per node
#define U_STR 264   // 256 + 8 pad (ushort)
#define H_STR 136   // 128 + 8 pad (ushort)
#define NRANGE 4    // dst ranges (dst re-read factor)
#define FILLB (NRANGE * 256)   // fill blocks in merged kernel

typedef __attribute__((ext_vector_type(8))) short short8v;            // 8 bf16
typedef __attribute__((ext_vector_type(4))) float float4v;            // MFMA acc
typedef __attribute__((ext_vector_type(8))) unsigned short ushort8v;  // 8 bf16
typedef __attribute__((ext_vector_type(4))) unsigned short ushort4v;  // 4 bf16

__device__ __forceinline__ unsigned short f2bf_rne(float f) {
    unsigned u = __float_as_uint(f);
    return (unsigned short)((u + 0x7fffu + ((u >> 16) & 1u)) >> 16);
}

__device__ __forceinline__ float bf2f(unsigned short u) {
    return __uint_as_float(((unsigned)u) << 16);
}

// ---------------- slim prep: weights + cursor zero + dtype detect ----------
__global__ void prep_init(const float* __restrict__ Wl, const float* __restrict__ Wr,
                          const float* __restrict__ Wg,
                          unsigned short* __restrict__ WcH,
                          unsigned short* __restrict__ WgH,
                          const void* ei, int twoE, int* flag,
                          int* __restrict__ cursor, int* ovcnt, int N) {
    size_t idx = (size_t)blockIdx.x * 256 + threadIdx.x;
    const size_t W1 = 128 * 256;
    const size_t W2 = W1 + 64 * 128;
    const size_t C2 = W2 + (size_t)((N + 3) >> 2);
    if (idx < W1) {
        int o = (int)(idx >> 8), k = (int)(idx & 255);
        float v = (k < 128) ? Wl[o * 128 + k] : Wr[o * 128 + (k - 128)];
        WcH[idx] = f2bf_rne(v);
    } else if (idx < W2) {
        size_t j = idx - W1;
        WgH[j] = f2bf_rne(Wg[j]);
    } else if (idx < C2) {
        size_t b = (idx - W2) * 4;
        if (b + 3 < (size_t)N) {
            *(int4*)(cursor + b) = make_int4(0, 0, 0, 0);
        } else {
            for (size_t j = b; j < (size_t)N && j < b + 4; ++j) cursor[j] = 0;
        }
    } else {
        if (threadIdx.x == 0) *ovcnt = 0;
        __shared__ int ok;
        if (threadIdx.x == 0) ok = 1;
        __syncthreads();
        const int* p = (const int*)ei;
        for (int k = threadIdx.x; k < 512; k += 256) {
            long long pos = 1 + ((long long)k * (long long)(twoE - 2)) / 512;
            pos |= 1;
            if (pos < twoE && p[pos] != 0) ok = 0;
        }
        __syncthreads();
        if (threadIdx.x == 0) *flag = ok;  // 1 => int64, 0 => int32
    }
}

// ---------------- merged: x->bf16 convert (first) + 4-range edge fill ------
__global__ void fill_convert(const void* __restrict__ ei, const int* __restrict__ flag,
                             int* __restrict__ cursor, int* __restrict__ colf,
                             int2* __restrict__ ovlist, int* __restrict__ ovcnt,
                             int E, int N,
                             const float* __restrict__ x,
                             unsigned short* __restrict__ xbf, size_t xElems,
                             int cblocks) {
    if (blockIdx.x < cblocks) {
        // ---- x -> bf16 convert (dispatches first: BW-bound, fills device)
        size_t idx = (size_t)blockIdx.x * 256 + threadIdx.x;
        size_t j = idx * 4;
        if (j < xElems) {
            float4 v = *(const float4*)(x + j);
            ushort4v o;
            o[0] = f2bf_rne(v.x);
            o[1] = f2bf_rne(v.y);
            o[2] = f2bf_rne(v.z);
            o[3] = f2bf_rne(v.w);
            *(ushort4v*)(xbf + j) = o;
        }
    } else {
        // ---- range-partitioned edge fill (backfills; latency hides under convert)
        int fb = blockIdx.x - cblocks;
        const int r = fb & (NRANGE - 1);
        const int slot = fb >> 2;           // NRANGE==4
        const int nslots = FILLB >> 2;      // 256
        const int lo = (int)((long long)r * N / NRANGE);
        const int hi = (int)((long long)(r + 1) * N / NRANGE);
        const int is64 = *flag;
        const int step = nslots * 256 * 4;

        auto process = [&](int d, int e) {
            if (d >= lo && d < hi) {
                int s = is64 ? (int)((const long long*)ei)[e] : ((const int*)ei)[e];
                int pos = atomicAdd(&cursor[d], 1);
                if (pos < FIX) {
                    colf[d * FIX + pos] = s;
                } else {
                    int o = atomicAdd(ovcnt, 1);
                    ovlist[o] = make_int2(d, s);
                }
            }
        };

        int base = (slot * 256 + threadIdx.x) * 4;
        for (; base + 3 < E; base += step) {
            int d0, d1, d2, d3;
            if (is64) {
                const long long* p = (const long long*)ei + E;
                d0 = (int)p[base];
                d1 = (int)p[base + 1];
                d2 = (int)p[base + 2];
                d3 = (int)p[base + 3];
            } else {
                const int* p = (const int*)ei + E;
                d0 = p[base];
                d1 = p[base + 1];
                d2 = p[base + 2];
                d3 = p[base + 3];
            }
            process(d0, base);
            process(d1, base + 1);
            process(d2, base + 2);
            process(d3, base + 3);
        }
        for (int e = base; e < E; ++e) {   // tail
            int d = is64 ? (int)((const long long*)ei)[E + e] : ((const int*)ei)[E + e];
            process(d, e);
        }
    }
}

// ---------------- gather mean: quarter-wave per node, col-prefetch ---------
__global__ void gather_mean(const int* __restrict__ degp, const int* __restrict__ colf,
                            const int2* __restrict__ ovlist, const int* __restrict__ ovcnt,
                            const unsigned short* __restrict__ xbf,
                            unsigned short* __restrict__ meanbf, int N) {
    int node = blockIdx.x * 16 + (threadIdx.x >> 4);
    if (node >= N) return;
    int lane = threadIdx.x & 63;
    int sl = lane & 15;
    int gb = lane & 48;   // quarter-group base lane
    int deg = degp[node];
    int nf = deg < FIX ? deg : FIX;

    int c0 = colf[node * FIX + sl];
    int c1 = (sl < 8) ? colf[node * FIX + 16 + sl] : 0;
    auto getcol = [&](int e) {
        return (e < 16) ? __shfl(c0, gb + e, 64) : __shfl(c1, gb + e - 16, 64);
    };

    float a0 = 0.f, a1 = 0.f, a2 = 0.f, a3 = 0.f, a4 = 0.f, a5 = 0.f, a6 = 0.f, a7 = 0.f;
    int e = 0;
    for (; e + 3 < nf; e += 4) {   // 4 row loads in flight
        int s0 = getcol(e), s1 = getcol(e + 1), s2 = getcol(e + 2), s3 = getcol(e + 3);
        ushort8v v0 = *(const ushort8v*)(xbf + (size_t)s0 * DIN + sl * 8);
        ushort8v v1 = *(const ushort8v*)(xbf + (size_t)s1 * DIN + sl * 8);
        ushort8v v2 = *(const ushort8v*)(xbf + (size_t)s2 * DIN + sl * 8);
        ushort8v v3 = *(const ushort8v*)(xbf + (size_t)s3 * DIN + sl * 8);
        a0 += bf2f(v0[0]) + bf2f(v1[0]) + bf2f(v2[0]) + bf2f(v3[0]);
        a1 += bf2f(v0[1]) + bf2f(v1[1]) + bf2f(v2[1]) + bf2f(v3[1]);
        a2 += bf2f(v0[2]) + bf2f(v1[2]) + bf2f(v2[2]) + bf2f(v3[2]);
        a3 += bf2f(v0[3]) + bf2f(v1[3]) + bf2f(v2[3]) + bf2f(v3[3]);
        a4 += bf2f(v0[4]) + bf2f(v1[4]) + bf2f(v2[4]) + bf2f(v3[4]);
        a5 += bf2f(v0[5]) + bf2f(v1[5]) + bf2f(v2[5]) + bf2f(v3[5]);
        a6 += bf2f(v0[6]) + bf2f(v1[6]) + bf2f(v2[6]) + bf2f(v3[6]);
        a7 += bf2f(v0[7]) + bf2f(v1[7]) + bf2f(v2[7]) + bf2f(v3[7]);
    }
    for (; e + 1 < nf; e += 2) {
        int s0 = getcol(e), s1 = getcol(e + 1);
        ushort8v v0 = *(const ushort8v*)(xbf + (size_t)s0 * DIN + sl * 8);
        ushort8v v1 = *(const ushort8v*)(xbf + (size_t)s1 * DIN + sl * 8);
        a0 += bf2f(v0[0]) + bf2f(v1[0]);
        a1 += bf2f(v0[1]) + bf2f(v1[1]);
        a2 += bf2f(v0[2]) + bf2f(v1[2]);
        a3 += bf2f(v0[3]) + bf2f(v1[3]);
        a4 += bf2f(v0[4]) + bf2f(v1[4]);
        a5 += bf2f(v0[5]) + bf2f(v1[5]);
        a6 += bf2f(v0[6]) + bf2f(v1[6]);
        a7 += bf2f(v0[7]) + bf2f(v1[7]);
    }
    if (e < nf) {
        int s0 = getcol(e);
        ushort8v v0 = *(const ushort8v*)(xbf + (size_t)s0 * DIN + sl * 8);
        a0 += bf2f(v0[0]); a1 += bf2f(v0[1]); a2 += bf2f(v0[2]); a3 += bf2f(v0[3]);
        a4 += bf2f(v0[4]); a5 += bf2f(v0[5]); a6 += bf2f(v0[6]); a7 += bf2f(v0[7]);
    }
    int oc = *ovcnt;
    for (int k = 0; k < oc; ++k) {       // normally oc == 0
        int2 pr = ovlist[k];
        if (pr.x == node) {
            ushort8v v = *(const ushort8v*)(xbf + (size_t)pr.y * DIN + sl * 8);
            a0 += bf2f(v[0]); a1 += bf2f(v[1]); a2 += bf2f(v[2]); a3 += bf2f(v[3]);
            a4 += bf2f(v[4]); a5 += bf2f(v[5]); a6 += bf2f(v[6]); a7 += bf2f(v[7]);
        }
    }
    float invd = (deg > 0) ? 1.0f / (float)deg : 0.f;
    ushort8v H;
    H[0] = f2bf_rne(a0 * invd); H[1] = f2bf_rne(a1 * invd);
    H[2] = f2bf_rne(a2 * invd); H[3] = f2bf_rne(a3 * invd);
    H[4] = f2bf_rne(a4 * invd); H[5] = f2bf_rne(a5 * invd);
    H[6] = f2bf_rne(a6 * invd); H[7] = f2bf_rne(a7 * invd);
    *(ushort8v*)(meanbf + (size_t)node * DIN + sl * 8) = H;
}

// ---------------- GEMM (swapped): h^T = Wcat*u^T; hw^T = dinv*(Wg*h^T) -----
__global__ __launch_bounds__(512, 4) void sage_gemm(
    const unsigned short* __restrict__ meanbf,
    const unsigned short* __restrict__ xbf,
    const unsigned short* __restrict__ WcH,
    const unsigned short* __restrict__ WgH,
    const float* __restrict__ bl, const int* __restrict__ degp,
    unsigned short* __restrict__ hwbf, int N, int ntiles)
{
    __shared__ unsigned short usH[2][32 * U_STR];
    __shared__ unsigned short hsH[2][32 * H_STR];
    const int tid = threadIdx.x;
    const int wave = tid >> 6;        // 0..7
    const int lane = tid & 63;
    const int lrow = lane & 15;       // A-row(feature) / B-col(node) / D-col(node)
    const int lk8  = (lane >> 4) << 3;
    const int qr   = (lane >> 4) << 2;

    // per-thread staging slots: idxA = tid, idxB = tid + 512 (32*32 = 1024)
    const int nA = tid >> 5,          cA = (tid & 31) << 3;
    const int nB = (tid + 512) >> 5,  cB = ((tid + 512) & 31) << 3;

    // ---- GEMM1 weights: 16 features per wave (32 VGPRs)
    const int f1 = wave * 16 + lrow;
    short8v B1[8];
#pragma unroll
    for (int ks = 0; ks < 8; ++ks) {
        B1[ks] = *(const short8v*)(WcH + f1 * 256 + ks * 32 + lk8);
    }
    // ---- GEMM2 weights: feature-tile (wave&3) (16 VGPRs)
    const int fw = (wave & 3) * 16;
    const int nw = (wave >> 2) * 16;
    const int f2 = fw + lrow;
    short8v B2[4];
#pragma unroll
    for (int ks = 0; ks < 4; ++ks) {
        B2[ks] = *(const short8v*)(WgH + f2 * 128 + ks * 32 + lk8);
    }
    const float4 bb = *(const float4*)(bl + wave * 16 + qr);

    auto loadA = [&](int tile) {
        int node = tile * NT + nA;
        if (node >= N) node = N - 1;
        return (cA < 128)
                   ? *(const short8v*)(meanbf + (size_t)node * DIN + cA)
                   : *(const short8v*)(xbf + (size_t)node * DIN + (cA - 128));
    };
    auto loadB = [&](int tile) {
        int node = tile * NT + nB;
        if (node >= N) node = N - 1;
        return (cB < 128)
                   ? *(const short8v*)(meanbf + (size_t)node * DIN + cB)
                   : *(const short8v*)(xbf + (size_t)node * DIN + (cB - 128));
    };

    int tile = blockIdx.x;
    if (tile >= ntiles) return;
    int buf = 0;
    {   // prologue: full stage of tile 0
        short8v sA = loadA(tile);
        short8v sB = loadB(tile);
        *(short8v*)(&usH[0][nA * U_STR + cA]) = sA;
        *(short8v*)(&usH[0][nB * U_STR + cB]) = sB;
    }
    __syncthreads();

    for (; tile < ntiles; tile += gridDim.x) {
        int nxt = tile + gridDim.x;
        bool hn = (nxt < ntiles);

        // ---- T14 stage-issue: loads for next tile (land under GEMM1's MFMAs)
        short8v sA, sB;
        if (hn) {
            sA = loadA(nxt);
            sB = loadB(nxt);
        }

        // ---- GEMM1: acc0 = W x u (nodes 0-15), acc1 = (nodes 16-31)
        float4v acc0 = {0.f, 0.f, 0.f, 0.f};
        float4v acc1 = {0.f, 0.f, 0.f, 0.f};
#pragma unroll
        for (int ks = 0; ks < 8; ++ks) {
            int kb = ks * 32 + lk8;
            short8v a0 = *(const short8v*)&usH[buf][lrow * U_STR + kb];
            short8v a1 = *(const short8v*)&usH[buf][(16 + lrow) * U_STR + kb];
            acc0 = __builtin_amdgcn_mfma_f32_16x16x32_bf16(B1[ks], a0, acc0, 0, 0, 0);
            acc1 = __builtin_amdgcn_mfma_f32_16x16x32_bf16(B1[ks], a1, acc1, 0, 0, 0);
        }
        __syncthreads();

        // ---- T14 stage-write: park staged regs in usH[buf^1]
        if (hn) {
            *(short8v*)(&usH[buf ^ 1][nA * U_STR + cA]) = sA;
            *(short8v*)(&usH[buf ^ 1][nB * U_STR + cB]) = sB;
        }

        // ---- bias + ReLU -> bf16 h (packed 8B writes): h[node][feat]
        {
            ushort4v p;
            p[0] = f2bf_rne(fmaxf(acc0[0] + bb.x, 0.f));
            p[1] = f2bf_rne(fmaxf(acc0[1] + bb.y, 0.f));
            p[2] = f2bf_rne(fmaxf(acc0[2] + bb.z, 0.f));
            p[3] = f2bf_rne(fmaxf(acc0[3] + bb.w, 0.f));
            *(ushort4v*)&hsH[buf][lrow * H_STR + wave * 16 + qr] = p;
            p[0] = f2bf_rne(fmaxf(acc1[0] + bb.x, 0.f));
            p[1] = f2bf_rne(fmaxf(acc1[1] + bb.y, 0.f));
            p[2] = f2bf_rne(fmaxf(acc1[2] + bb.z, 0.f));
            p[3] = f2bf_rne(fmaxf(acc1[3] + bb.w, 0.f));
            *(ushort4v*)&hsH[buf][(16 + lrow) * H_STR + wave * 16 + qr] = p;
        }
        __syncthreads();

        // ---- GEMM2: acc2 = Wg x h  (feature-tile fw, node-tile nw)
        float4v acc2 = {0.f, 0.f, 0.f, 0.f};
#pragma unroll
        for (int ks = 0; ks < 4; ++ks) {
            int kb = ks * 32 + lk8;
            short8v a = *(const short8v*)&hsH[buf][(nw + lrow) * H_STR + kb];
            acc2 = __builtin_amdgcn_mfma_f32_16x16x32_bf16(B2[ks], a, acc2, 0, 0, 0);
        }

        // ---- write hw bf16 packed, PRE-SCALED by dinv[node]=rsqrt(deg+1)
        {
            int node = tile * NT + nw + lrow;
            if (node < N) {
                float dv = rsqrtf((float)degp[node] + 1.0f);
                ushort4v p;
                p[0] = f2bf_rne(dv * acc2[0]);
                p[1] = f2bf_rne(dv * acc2[1]);
                p[2] = f2bf_rne(dv * acc2[2]);
                p[3] = f2bf_rne(dv * acc2[3]);
                *(ushort4v*)(hwbf + (size_t)node * DOUT + fw + qr) = p;
            }
        }
        buf ^= 1;
    }
}

// ---------------- gather GCN + softmax: quarter-wave per node --------------
__global__ void gather_gcn_softmax(const int* __restrict__ degp, const int* __restrict__ colf,
                                   const int2* __restrict__ ovlist, const int* __restrict__ ovcnt,
                                   const unsigned short* __restrict__ hwbf,
                                   const float* __restrict__ bg,
                                   float* __restrict__ out, float* __restrict__ soft, int N) {
    int node = blockIdx.x * 16 + (threadIdx.x >> 4);
    if (node >= N) return;
    int lane = threadIdx.x & 63;
    int sl = lane & 15;
    int gb = lane & 48;
    int deg = degp[node];
    int nf = deg < FIX ? deg : FIX;

    int c0 = colf[node * FIX + sl];
    int c1 = (sl < 8) ? colf[node * FIX + 16 + sl] : 0;
    auto getcol = [&](int e) {
        return (e < 16) ? __shfl(c0, gb + e, 64) : __shfl(c1, gb + e - 16, 64);
    };

    // self term (pre-scaled) starts the accumulator
    ushort4v sv = *(const ushort4v*)(hwbf + (size_t)node * DOUT + sl * 4);
    float a0 = bf2f(sv[0]), a1 = bf2f(sv[1]), a2 = bf2f(sv[2]), a3 = bf2f(sv[3]);

    int e = 0;
    for (; e + 3 < nf; e += 4) {   // 4 row loads in flight
        int s0 = getcol(e), s1 = getcol(e + 1), s2 = getcol(e + 2), s3 = getcol(e + 3);
        ushort4v v0 = *(const ushort4v*)(hwbf + (size_t)s0 * DOUT + sl * 4);
        ushort4v v1 = *(const ushort4v*)(hwbf + (size_t)s1 * DOUT + sl * 4);
        ushort4v v2 = *(const ushort4v*)(hwbf + (size_t)s2 * DOUT + sl * 4);
        ushort4v v3 = *(const ushort4v*)(hwbf + (size_t)s3 * DOUT + sl * 4);
        a0 += bf2f(v0[0]) + bf2f(v1[0]) + bf2f(v2[0]) + bf2f(v3[0]);
        a1 += bf2f(v0[1]) + bf2f(v1[1]) + bf2f(v2[1]) + bf2f(v3[1]);
        a2 += bf2f(v0[2]) + bf2f(v1[2]) + bf2f(v2[2]) + bf2f(v3[2]);
        a3 += bf2f(v0[3]) + bf2f(v1[3]) + bf2f(v2[3]) + bf2f(v3[3]);
    }
    for (; e + 1 < nf; e += 2) {
        int s0 = getcol(e), s1 = getcol(e + 1);
        ushort4v v0 = *(const ushort4v*)(hwbf + (size_t)s0 * DOUT + sl * 4);
        ushort4v v1 = *(const ushort4v*)(hwbf + (size_t)s1 * DOUT + sl * 4);
        a0 += bf2f(v0[0]) + bf2f(v1[0]);
        a1 += bf2f(v0[1]) + bf2f(v1[1]);
        a2 += bf2f(v0[2]) + bf2f(v1[2]);
        a3 += bf2f(v0[3]) + bf2f(v1[3]);
    }
    if (e < nf) {
        int s0 = getcol(e);
        ushort4v v0 = *(const ushort4v*)(hwbf + (size_t)s0 * DOUT + sl * 4);
        a0 += bf2f(v0[0]);
        a1 += bf2f(v0[1]);
        a2 += bf2f(v0[2]);
        a3 += bf2f(v0[3]);
    }
    int oc = *ovcnt;
    for (int k = 0; k < oc; ++k) {       // normally oc == 0
        int2 pr = ovlist[k];
        if (pr.x == node) {
            ushort4v v = *(const ushort4v*)(hwbf + (size_t)pr.y * DOUT + sl * 4);
            a0 += bf2f(v[0]);
            a1 += bf2f(v[1]);
            a2 += bf2f(v[2]);
            a3 += bf2f(v[3]);
        }
    }

    float di = rsqrtf((float)deg + 1.0f);
    float4 bb = *(const float4*)(bg + sl * 4);
    float v0 = di * a0 + bb.x;
    float v1 = di * a1 + bb.y;
    float v2 = di * a2 + bb.z;
    float v3 = di * a3 + bb.w;

    // softmax over 64 cols held by 16 lanes x 4
    float m = fmaxf(fmaxf(v0, v1), fmaxf(v2, v3));
#pragma unroll
    for (int mask = 8; mask; mask >>= 1) m = fmaxf(m, __shfl_xor(m, mask, 64));
    float e0 = __expf(v0 - m), e1 = __expf(v1 - m), e2 = __expf(v2 - m), e3 = __expf(v3 - m);
    float s = e0 + e1 + e2 + e3;
#pragma unroll
    for (int mask = 8; mask; mask >>= 1) s += __shfl_xor(s, mask, 64);
    float inv = 1.0f / s;
    *(float4*)(out + (size_t)node * DOUT + sl * 4) = make_float4(v0, v1, v2, v3);
    *(float4*)(soft + (size_t)node * DOUT + sl * 4) =
        make_float4(e0 * inv, e1 * inv, e2 * inv, e3 * inv);
}

// ---------------------------------------------------------------------------
extern "C" void kernel_launch(void* const* d_in, const int* in_sizes, int n_in,
                              void* d_out, int out_size, void* d_ws, size_t ws_size,
                              hipStream_t stream) {
    const float* x  = (const float*)d_in[0];
    const void*  ei = d_in[1];
    const float* Wl = (const float*)d_in[2];
    const float* bl = (const float*)d_in[3];
    const float* Wr = (const float*)d_in[4];
    const float* Wg = (const float*)d_in[5];
    const float* bg = (const float*)d_in[6];
    const int N = in_sizes[0] / DIN;
    const int E = in_sizes[1] / 2;
    float* out = (float*)d_out;

    char* ws = (char*)d_ws;
    size_t off = 0;
    auto alloc = [&](size_t bytes) {
        void* p = ws + off;
        off += (bytes + 255) / 256 * 256;
        return p;
    };
    int*   flag    = (int*)alloc(4);
    int*   ovcnt   = (int*)alloc(4);
    int*   cursor  = (int*)alloc((size_t)N * 4);          // becomes deg
    int*   colf    = (int*)alloc((size_t)N * FIX * 4);    // fixed adjacency
    int2*  ovlist  = (int2*)alloc((size_t)E * 8);         // overflow pairs
    unsigned short* WcH = (unsigned short*)alloc(128 * 256 * 2);
    unsigned short* WgH = (unsigned short*)alloc(64 * 128 * 2);
    unsigned short* xbf    = (unsigned short*)alloc((size_t)N * DIN * 2);
    unsigned short* meanbf = (unsigned short*)alloc((size_t)N * DIN * 2);
    unsigned short* hwbf   = (unsigned short*)alloc((size_t)N * DOUT * 2);
    (void)ws_size; (void)n_in; (void)out_size;

    float* soft = out + (size_t)N * DOUT;

    const int ntiles = (N + NT - 1) / NT;
    const int ggrid = ntiles < 512 ? ntiles : 512;
    const size_t xElems = (size_t)N * DIN;

    {
        size_t total = 128 * 256 + 64 * 128 + (size_t)((N + 3) >> 2);
        int blocks = (int)((total + 255) / 256) + 1;   // +1 detect block
        prep_init<<<blocks, 256, 0, stream>>>(Wl, Wr, Wg, WcH, WgH,
                                              ei, 2 * E, flag, cursor, ovcnt, N);
    }
    {
        int cblocks = (int)(((xElems >> 2) + 255) / 256);
        fill_convert<<<cblocks + FILLB, 256, 0, stream>>>(ei, flag, cursor, colf,
                                                          ovlist, ovcnt, E, N,
                                                          x, xbf, xElems, cblocks);
    }
    gather_mean<<<(N + 15) / 16, 256, 0, stream>>>(cursor, colf, ovlist, ovcnt, xbf, meanbf, N);
    sage_gemm<<<ggrid, 512, 0, stream>>>(meanbf, xbf, WcH, WgH, bl, cursor, hwbf, N, ntiles);
    gather_gcn_softmax<<<(N + 15) / 16, 256, 0, stream>>>(cursor, colf, ovlist, ovcnt, hwbf, bg, out, soft, N);
}

// Round 21
// 117.530 us; speedup vs baseline: 1.0635x; 1.0635x over previous
//
#include <hip/hip_runtime.h>
#include <math.h>

// GraphSAGE (mean) + GCN + softmax. Activations AND weights RNE-bf16
// (single-term), f32 accumulate via MFMA (operand-swapped: A=weights,
// B=activations). hw stored pre-scaled by dinv. Fixed-stride adjacency
// (24 slots/node) + overflow list. Edge-fill (batched loads, 4 independent
// atomic chains, 2048 blocks) + x->bf16 convert in ONE merged dispatch.
// Gathers: col-prefetch + shfl broadcast, 4-deep pipeline.
// sage_gemm: T14 async-STAGE split.  [R19 configuration — measured optimum]
// N=100000, E=625000, D_IN=D_H=128, D_OUT=64 (derived from in_sizes).

#define DIN 128
#define DH  128
#define DOUT 64
#define NT  32      // nodes per GEMM tile
#define FIX 24      // fixed adjacency slots per node
#define U_STR 264   // 256 + 8 pad (ushort)
#define H_STR 136   // 128 + 8 pad (ushort)
#define FILLB 2048  // fill blocks in merged kernel (8 XCD ranges x 256 slots)

typedef __attribute__((ext_vector_type(8))) short short8v;            // 8 bf16
typedef __attribute__((ext_vector_type(4))) float float4v;            // MFMA acc
typedef __attribute__((ext_vector_type(8))) unsigned short ushort8v;  // 8 bf16
typedef __attribute__((ext_vector_type(4))) unsigned short ushort4v;  // 4 bf16

__device__ __forceinline__ unsigned short f2bf_rne(float f) {
    unsigned u = __float_as_uint(f);
    return (unsigned short)((u + 0x7fffu + ((u >> 16) & 1u)) >> 16);
}

__device__ __forceinline__ float bf2f(unsigned short u) {
    return __uint_as_float(((unsigned)u) << 16);
}

// ---------------- slim prep: weights + cursor zero + dtype detect ----------
__global__ void prep_init(const float* __restrict__ Wl, const float* __restrict__ Wr,
                          const float* __restrict__ Wg,
                          unsigned short* __restrict__ WcH,
                          unsigned short* __restrict__ WgH,
                          const void* ei, int twoE, int* flag,
                          int* __restrict__ cursor, int* ovcnt, int N) {
    size_t idx = (size_t)blockIdx.x * 256 + threadIdx.x;
    const size_t W1 = 128 * 256;
    const size_t W2 = W1 + 64 * 128;
    const size_t C2 = W2 + (size_t)((N + 3) >> 2);
    if (idx < W1) {
        int o = (int)(idx >> 8), k = (int)(idx & 255);
        float v = (k < 128) ? Wl[o * 128 + k] : Wr[o * 128 + (k - 128)];
        WcH[idx] = f2bf_rne(v);
    } else if (idx < W2) {
        size_t j = idx - W1;
        WgH[j] = f2bf_rne(Wg[j]);
    } else if (idx < C2) {
        size_t b = (idx - W2) * 4;
        if (b + 3 < (size_t)N) {
            *(int4*)(cursor + b) = make_int4(0, 0, 0, 0);
        } else {
            for (size_t j = b; j < (size_t)N && j < b + 4; ++j) cursor[j] = 0;
        }
    } else {
        if (threadIdx.x == 0) *ovcnt = 0;
        __shared__ int ok;
        if (threadIdx.x == 0) ok = 1;
        __syncthreads();
        const int* p = (const int*)ei;
        for (int k = threadIdx.x; k < 512; k += 256) {
            long long pos = 1 + ((long long)k * (long long)(twoE - 2)) / 512;
            pos |= 1;
            if (pos < twoE && p[pos] != 0) ok = 0;
        }
        __syncthreads();
        if (threadIdx.x == 0) *flag = ok;  // 1 => int64, 0 => int32
    }
}

// ---------------- merged: adjacency fill (blocks < FILLB) + x->bf16 --------
__global__ void fill_convert(const void* __restrict__ ei, const int* __restrict__ flag,
                             int* __restrict__ cursor, int* __restrict__ colf,
                             int2* __restrict__ ovlist, int* __restrict__ ovcnt,
                             int E, int N,
                             const float* __restrict__ x,
                             unsigned short* __restrict__ xbf, size_t xElems) {
    if (blockIdx.x < FILLB) {
        // ---- XCD-partitioned edge fill, batched loads, independent chains
        const int r = blockIdx.x & 7;
        const int slot = blockIdx.x >> 3;
        const int nslots = FILLB >> 3;           // 256
        const int lo = (int)((long long)r * N / 8);
        const int hi = (int)((long long)(r + 1) * N / 8);
        const int is64 = *flag;
        const int step = nslots * 256 * 4;       // 262144

        auto process = [&](int d, int e) {
            if (d >= lo && d < hi) {
                int s = is64 ? (int)((const long long*)ei)[e] : ((const int*)ei)[e];
                int pos = atomicAdd(&cursor[d], 1);
                if (pos < FIX) {
                    colf[d * FIX + pos] = s;
                } else {
                    int o = atomicAdd(ovcnt, 1);
                    ovlist[o] = make_int2(d, s);
                }
            }
        };

        int base = (slot * 256 + threadIdx.x) * 4;
        for (; base + 3 < E; base += step) {
            int d0, d1, d2, d3;
            if (is64) {
                const long long* p = (const long long*)ei + E;
                d0 = (int)p[base];
                d1 = (int)p[base + 1];
                d2 = (int)p[base + 2];
                d3 = (int)p[base + 3];
            } else {
                const int* p = (const int*)ei + E;
                d0 = p[base];
                d1 = p[base + 1];
                d2 = p[base + 2];
                d3 = p[base + 3];
            }
            process(d0, base);
            process(d1, base + 1);
            process(d2, base + 2);
            process(d3, base + 3);
        }
        for (int e = base; e < E; ++e) {   // tail (only last trip)
            int d = is64 ? (int)((const long long*)ei)[E + e] : ((const int*)ei)[E + e];
            process(d, e);
        }
    } else {
        // ---- x -> bf16 convert (independent of fill)
        size_t idx = (size_t)(blockIdx.x - FILLB) * 256 + threadIdx.x;
        size_t j = idx * 4;
        if (j < xElems) {
            float4 v = *(const float4*)(x + j);
            ushort4v o;
            o[0] = f2bf_rne(v.x);
            o[1] = f2bf_rne(v.y);
            o[2] = f2bf_rne(v.z);
            o[3] = f2bf_rne(v.w);
            *(ushort4v*)(xbf + j) = o;
        }
    }
}

// ---------------- gather mean: quarter-wave per node, col-prefetch ---------
__global__ void gather_mean(const int* __restrict__ degp, const int* __restrict__ colf,
                            const int2* __restrict__ ovlist, const int* __restrict__ ovcnt,
                            const unsigned short* __restrict__ xbf,
                            unsigned short* __restrict__ meanbf, int N) {
    int node = blockIdx.x * 16 + (threadIdx.x >> 4);
    if (node >= N) return;
    int lane = threadIdx.x & 63;
    int sl = lane & 15;
    int gb = lane & 48;   // quarter-group base lane
    int deg = degp[node];
    int nf = deg < FIX ? deg : FIX;

    int c0 = colf[node * FIX + sl];
    int c1 = (sl < 8) ? colf[node * FIX + 16 + sl] : 0;
    auto getcol = [&](int e) {
        return (e < 16) ? __shfl(c0, gb + e, 64) : __shfl(c1, gb + e - 16, 64);
    };

    float a0 = 0.f, a1 = 0.f, a2 = 0.f, a3 = 0.f, a4 = 0.f, a5 = 0.f, a6 = 0.f, a7 = 0.f;
    int e = 0;
    for (; e + 3 < nf; e += 4) {   // 4 row loads in flight
        int s0 = getcol(e), s1 = getcol(e + 1), s2 = getcol(e + 2), s3 = getcol(e + 3);
        ushort8v v0 = *(const ushort8v*)(xbf + (size_t)s0 * DIN + sl * 8);
        ushort8v v1 = *(const ushort8v*)(xbf + (size_t)s1 * DIN + sl * 8);
        ushort8v v2 = *(const ushort8v*)(xbf + (size_t)s2 * DIN + sl * 8);
        ushort8v v3 = *(const ushort8v*)(xbf + (size_t)s3 * DIN + sl * 8);
        a0 += bf2f(v0[0]) + bf2f(v1[0]) + bf2f(v2[0]) + bf2f(v3[0]);
        a1 += bf2f(v0[1]) + bf2f(v1[1]) + bf2f(v2[1]) + bf2f(v3[1]);
        a2 += bf2f(v0[2]) + bf2f(v1[2]) + bf2f(v2[2]) + bf2f(v3[2]);
        a3 += bf2f(v0[3]) + bf2f(v1[3]) + bf2f(v2[3]) + bf2f(v3[3]);
        a4 += bf2f(v0[4]) + bf2f(v1[4]) + bf2f(v2[4]) + bf2f(v3[4]);
        a5 += bf2f(v0[5]) + bf2f(v1[5]) + bf2f(v2[5]) + bf2f(v3[5]);
        a6 += bf2f(v0[6]) + bf2f(v1[6]) + bf2f(v2[6]) + bf2f(v3[6]);
        a7 += bf2f(v0[7]) + bf2f(v1[7]) + bf2f(v2[7]) + bf2f(v3[7]);
    }
    for (; e + 1 < nf; e += 2) {
        int s0 = getcol(e), s1 = getcol(e + 1);
        ushort8v v0 = *(const ushort8v*)(xbf + (size_t)s0 * DIN + sl * 8);
        ushort8v v1 = *(const ushort8v*)(xbf + (size_t)s1 * DIN + sl * 8);
        a0 += bf2f(v0[0]) + bf2f(v1[0]);
        a1 += bf2f(v0[1]) + bf2f(v1[1]);
        a2 += bf2f(v0[2]) + bf2f(v1[2]);
        a3 += bf2f(v0[3]) + bf2f(v1[3]);
        a4 += bf2f(v0[4]) + bf2f(v1[4]);
        a5 += bf2f(v0[5]) + bf2f(v1[5]);
        a6 += bf2f(v0[6]) + bf2f(v1[6]);
        a7 += bf2f(v0[7]) + bf2f(v1[7]);
    }
    if (e < nf) {
        int s0 = getcol(e);
        ushort8v v0 = *(const ushort8v*)(xbf + (size_t)s0 * DIN + sl * 8);
        a0 += bf2f(v0[0]); a1 += bf2f(v0[1]); a2 += bf2f(v0[2]); a3 += bf2f(v0[3]);
        a4 += bf2f(v0[4]); a5 += bf2f(v0[5]); a6 += bf2f(v0[6]); a7 += bf2f(v0[7]);
    }
    int oc = *ovcnt;
    for (int k = 0; k < oc; ++k) {       // normally oc == 0
        int2 pr = ovlist[k];
        if (pr.x == node) {
            ushort8v v = *(const ushort8v*)(xbf + (size_t)pr.y * DIN + sl * 8);
            a0 += bf2f(v[0]); a1 += bf2f(v[1]); a2 += bf2f(v[2]); a3 += bf2f(v[3]);
            a4 += bf2f(v[4]); a5 += bf2f(v[5]); a6 += bf2f(v[6]); a7 += bf2f(v[7]);
        }
    }
    float invd = (deg > 0) ? 1.0f / (float)deg : 0.f;
    ushort8v H;
    H[0] = f2bf_rne(a0 * invd); H[1] = f2bf_rne(a1 * invd);
    H[2] = f2bf_rne(a2 * invd); H[3] = f2bf_rne(a3 * invd);
    H[4] = f2bf_rne(a4 * invd); H[5] = f2bf_rne(a5 * invd);
    H[6] = f2bf_rne(a6 * invd); H[7] = f2bf_rne(a7 * invd);
    *(ushort8v*)(meanbf + (size_t)node * DIN + sl * 8) = H;
}

// ---------------- GEMM (swapped): h^T = Wcat*u^T; hw^T = dinv*(Wg*h^T) -----
__global__ __launch_bounds__(512, 4) void sage_gemm(
    const unsigned short* __restrict__ meanbf,
    const unsigned short* __restrict__ xbf,
    const unsigned short* __restrict__ WcH,
    const unsigned short* __restrict__ WgH,
    const float* __restrict__ bl, const int* __restrict__ degp,
    unsigned short* __restrict__ hwbf, int N, int ntiles)
{
    __shared__ unsigned short usH[2][32 * U_STR];
    __shared__ unsigned short hsH[2][32 * H_STR];
    const int tid = threadIdx.x;
    const int wave = tid >> 6;        // 0..7
    const int lane = tid & 63;
    const int lrow = lane & 15;       // A-row(feature) / B-col(node) / D-col(node)
    const int lk8  = (lane >> 4) << 3;
    const int qr   = (lane >> 4) << 2;

    // per-thread staging slots: idxA = tid, idxB = tid + 512 (32*32 = 1024)
    const int nA = tid >> 5,          cA = (tid & 31) << 3;
    const int nB = (tid + 512) >> 5,  cB = ((tid + 512) & 31) << 3;

    // ---- GEMM1 weights: 16 features per wave (32 VGPRs)
    const int f1 = wave * 16 + lrow;
    short8v B1[8];
#pragma unroll
    for (int ks = 0; ks < 8; ++ks) {
        B1[ks] = *(const short8v*)(WcH + f1 * 256 + ks * 32 + lk8);
    }
    // ---- GEMM2 weights: feature-tile (wave&3) (16 VGPRs)
    const int fw = (wave & 3) * 16;
    const int nw = (wave >> 2) * 16;
    const int f2 = fw + lrow;
    short8v B2[4];
#pragma unroll
    for (int ks = 0; ks < 4; ++ks) {
        B2[ks] = *(const short8v*)(WgH + f2 * 128 + ks * 32 + lk8);
    }
    const float4 bb = *(const float4*)(bl + wave * 16 + qr);

    auto loadA = [&](int tile) {
        int node = tile * NT + nA;
        if (node >= N) node = N - 1;
        return (cA < 128)
                   ? *(const short8v*)(meanbf + (size_t)node * DIN + cA)
                   : *(const short8v*)(xbf + (size_t)node * DIN + (cA - 128));
    };
    auto loadB = [&](int tile) {
        int node = tile * NT + nB;
        if (node >= N) node = N - 1;
        return (cB < 128)
                   ? *(const short8v*)(meanbf + (size_t)node * DIN + cB)
                   : *(const short8v*)(xbf + (size_t)node * DIN + (cB - 128));
    };

    int tile = blockIdx.x;
    if (tile >= ntiles) return;
    int buf = 0;
    {   // prologue: full stage of tile 0
        short8v sA = loadA(tile);
        short8v sB = loadB(tile);
        *(short8v*)(&usH[0][nA * U_STR + cA]) = sA;
        *(short8v*)(&usH[0][nB * U_STR + cB]) = sB;
    }
    __syncthreads();

    for (; tile < ntiles; tile += gridDim.x) {
        int nxt = tile + gridDim.x;
        bool hn = (nxt < ntiles);

        // ---- T14 stage-issue: loads for next tile (land under GEMM1's MFMAs)
        short8v sA, sB;
        if (hn) {
            sA = loadA(nxt);
            sB = loadB(nxt);
        }

        // ---- GEMM1: acc0 = W x u (nodes 0-15), acc1 = (nodes 16-31)
        float4v acc0 = {0.f, 0.f, 0.f, 0.f};
        float4v acc1 = {0.f, 0.f, 0.f, 0.f};
#pragma unroll
        for (int ks = 0; ks < 8; ++ks) {
            int kb = ks * 32 + lk8;
            short8v a0 = *(const short8v*)&usH[buf][lrow * U_STR + kb];
            short8v a1 = *(const short8v*)&usH[buf][(16 + lrow) * U_STR + kb];
            acc0 = __builtin_amdgcn_mfma_f32_16x16x32_bf16(B1[ks], a0, acc0, 0, 0, 0);
            acc1 = __builtin_amdgcn_mfma_f32_16x16x32_bf16(B1[ks], a1, acc1, 0, 0, 0);
        }
        __syncthreads();

        // ---- T14 stage-write: park staged regs in usH[buf^1]
        if (hn) {
            *(short8v*)(&usH[buf ^ 1][nA * U_STR + cA]) = sA;
            *(short8v*)(&usH[buf ^ 1][nB * U_STR + cB]) = sB;
        }

        // ---- bias + ReLU -> bf16 h (packed 8B writes): h[node][feat]
        {
            ushort4v p;
            p[0] = f2bf_rne(fmaxf(acc0[0] + bb.x, 0.f));
            p[1] = f2bf_rne(fmaxf(acc0[1] + bb.y, 0.f));
            p[2] = f2bf_rne(fmaxf(acc0[2] + bb.z, 0.f));
            p[3] = f2bf_rne(fmaxf(acc0[3] + bb.w, 0.f));
            *(ushort4v*)&hsH[buf][lrow * H_STR + wave * 16 + qr] = p;
            p[0] = f2bf_rne(fmaxf(acc1[0] + bb.x, 0.f));
            p[1] = f2bf_rne(fmaxf(acc1[1] + bb.y, 0.f));
            p[2] = f2bf_rne(fmaxf(acc1[2] + bb.z, 0.f));
            p[3] = f2bf_rne(fmaxf(acc1[3] + bb.w, 0.f));
            *(ushort4v*)&hsH[buf][(16 + lrow) * H_STR + wave * 16 + qr] = p;
        }
        __syncthreads();

        // ---- GEMM2: acc2 = Wg x h  (feature-tile fw, node-tile nw)
        float4v acc2 = {0.f, 0.f, 0.f, 0.f};
#pragma unroll
        for (int ks = 0; ks < 4; ++ks) {
            int kb = ks * 32 + lk8;
            short8v a = *(const short8v*)&hsH[buf][(nw + lrow) * H_STR + kb];
            acc2 = __builtin_amdgcn_mfma_f32_16x16x32_bf16(B2[ks], a, acc2, 0, 0, 0);
        }

        // ---- write hw bf16 packed, PRE-SCALED by dinv[node]=rsqrt(deg+1)
        {
            int node = tile * NT + nw + lrow;
            if (node < N) {
                float dv = rsqrtf((float)degp[node] + 1.0f);
                ushort4v p;
                p[0] = f2bf_rne(dv * acc2[0]);
                p[1] = f2bf_rne(dv * acc2[1]);
                p[2] = f2bf_rne(dv * acc2[2]);
                p[3] = f2bf_rne(dv * acc2[3]);
                *(ushort4v*)(hwbf + (size_t)node * DOUT + fw + qr) = p;
            }
        }
        buf ^= 1;
    }
}

// ---------------- gather GCN + softmax: quarter-wave per node --------------
__global__ void gather_gcn_softmax(const int* __restrict__ degp, const int* __restrict__ colf,
                                   const int2* __restrict__ ovlist, const int* __restrict__ ovcnt,
                                   const unsigned short* __restrict__ hwbf,
                                   const float* __restrict__ bg,
                                   float* __restrict__ out, float* __restrict__ soft, int N) {
    int node = blockIdx.x * 16 + (threadIdx.x >> 4);
    if (node >= N) return;
    int lane = threadIdx.x & 63;
    int sl = lane & 15;
    int gb = lane & 48;
    int deg = degp[node];
    int nf = deg < FIX ? deg : FIX;

    int c0 = colf[node * FIX + sl];
    int c1 = (sl < 8) ? colf[node * FIX + 16 + sl] : 0;
    auto getcol = [&](int e) {
        return (e < 16) ? __shfl(c0, gb + e, 64) : __shfl(c1, gb + e - 16, 64);
    };

    // self term (pre-scaled) starts the accumulator
    ushort4v sv = *(const ushort4v*)(hwbf + (size_t)node * DOUT + sl * 4);
    float a0 = bf2f(sv[0]), a1 = bf2f(sv[1]), a2 = bf2f(sv[2]), a3 = bf2f(sv[3]);

    int e = 0;
    for (; e + 3 < nf; e += 4) {   // 4 row loads in flight
        int s0 = getcol(e), s1 = getcol(e + 1), s2 = getcol(e + 2), s3 = getcol(e + 3);
        ushort4v v0 = *(const ushort4v*)(hwbf + (size_t)s0 * DOUT + sl * 4);
        ushort4v v1 = *(const ushort4v*)(hwbf + (size_t)s1 * DOUT + sl * 4);
        ushort4v v2 = *(const ushort4v*)(hwbf + (size_t)s2 * DOUT + sl * 4);
        ushort4v v3 = *(const ushort4v*)(hwbf + (size_t)s3 * DOUT + sl * 4);
        a0 += bf2f(v0[0]) + bf2f(v1[0]) + bf2f(v2[0]) + bf2f(v3[0]);
        a1 += bf2f(v0[1]) + bf2f(v1[1]) + bf2f(v2[1]) + bf2f(v3[1]);
        a2 += bf2f(v0[2]) + bf2f(v1[2]) + bf2f(v2[2]) + bf2f(v3[2]);
        a3 += bf2f(v0[3]) + bf2f(v1[3]) + bf2f(v2[3]) + bf2f(v3[3]);
    }
    for (; e + 1 < nf; e += 2) {
        int s0 = getcol(e), s1 = getcol(e + 1);
        ushort4v v0 = *(const ushort4v*)(hwbf + (size_t)s0 * DOUT + sl * 4);
        ushort4v v1 = *(const ushort4v*)(hwbf + (size_t)s1 * DOUT + sl * 4);
        a0 += bf2f(v0[0]) + bf2f(v1[0]);
        a1 += bf2f(v0[1]) + bf2f(v1[1]);
        a2 += bf2f(v0[2]) + bf2f(v1[2]);
        a3 += bf2f(v0[3]) + bf2f(v1[3]);
    }
    if (e < nf) {
        int s0 = getcol(e);
        ushort4v v0 = *(const ushort4v*)(hwbf + (size_t)s0 * DOUT + sl * 4);
        a0 += bf2f(v0[0]);
        a1 += bf2f(v0[1]);
        a2 += bf2f(v0[2]);
        a3 += bf2f(v0[3]);
    }
    int oc = *ovcnt;
    for (int k = 0; k < oc; ++k) {       // normally oc == 0
        int2 pr = ovlist[k];
        if (pr.x == node) {
            ushort4v v = *(const ushort4v*)(hwbf + (size_t)pr.y * DOUT + sl * 4);
            a0 += bf2f(v[0]);
            a1 += bf2f(v[1]);
            a2 += bf2f(v[2]);
            a3 += bf2f(v[3]);
        }
    }

    float di = rsqrtf((float)deg + 1.0f);
    float4 bb = *(const float4*)(bg + sl * 4);
    float v0 = di * a0 + bb.x;
    float v1 = di * a1 + bb.y;
    float v2 = di * a2 + bb.z;
    float v3 = di * a3 + bb.w;

    // softmax over 64 cols held by 16 lanes x 4
    float m = fmaxf(fmaxf(v0, v1), fmaxf(v2, v3));
#pragma unroll
    for (int mask = 8; mask; mask >>= 1) m = fmaxf(m, __shfl_xor(m, mask, 64));
    float e0 = __expf(v0 - m), e1 = __expf(v1 - m), e2 = __expf(v2 - m), e3 = __expf(v3 - m);
    float s = e0 + e1 + e2 + e3;
#pragma unroll
    for (int mask = 8; mask; mask >>= 1) s += __shfl_xor(s, mask, 64);
    float inv = 1.0f / s;
    *(float4*)(out + (size_t)node * DOUT + sl * 4) = make_float4(v0, v1, v2, v3);
    *(float4*)(soft + (size_t)node * DOUT + sl * 4) =
        make_float4(e0 * inv, e1 * inv, e2 * inv, e3 * inv);
}

// ---------------------------------------------------------------------------
extern "C" void kernel_launch(void* const* d_in, const int* in_sizes, int n_in,
                              void* d_out, int out_size, void* d_ws, size_t ws_size,
                              hipStream_t stream) {
    const float* x  = (const float*)d_in[0];
    const void*  ei = d_in[1];
    const float* Wl = (const float*)d_in[2];
    const float* bl = (const float*)d_in[3];
    const float* Wr = (const float*)d_in[4];
    const float* Wg = (const float*)d_in[5];
    const float* bg = (const float*)d_in[6];
    const int N = in_sizes[0] / DIN;
    const int E = in_sizes[1] / 2;
    float* out = (float*)d_out;

    char* ws = (char*)d_ws;
    size_t off = 0;
    auto alloc = [&](size_t bytes) {
        void* p = ws + off;
        off += (bytes + 255) / 256 * 256;
        return p;
    };
    int*   flag    = (int*)alloc(4);
    int*   ovcnt   = (int*)alloc(4);
    int*   cursor  = (int*)alloc((size_t)N * 4);          // becomes deg
    int*   colf    = (int*)alloc((size_t)N * FIX * 4);    // fixed adjacency
    int2*  ovlist  = (int2*)alloc((size_t)E * 8);         // overflow pairs
    unsigned short* WcH = (unsigned short*)alloc(128 * 256 * 2);
    unsigned short* WgH = (unsigned short*)alloc(64 * 128 * 2);
    unsigned short* xbf    = (unsigned short*)alloc((size_t)N * DIN * 2);
    unsigned short* meanbf = (unsigned short*)alloc((size_t)N * DIN * 2);
    unsigned short* hwbf   = (unsigned short*)alloc((size_t)N * DOUT * 2);
    (void)ws_size; (void)n_in; (void)out_size;

    float* soft = out + (size_t)N * DOUT;

    const int ntiles = (N + NT - 1) / NT;
    const int ggrid = ntiles < 512 ? ntiles : 512;
    const size_t xElems = (size_t)N * DIN;

    {
        size_t total = 128 * 256 + 64 * 128 + (size_t)((N + 3) >> 2);
        int blocks = (int)((total + 255) / 256) + 1;   // +1 detect block
        prep_init<<<blocks, 256, 0, stream>>>(Wl, Wr, Wg, WcH, WgH,
                                              ei, 2 * E, flag, cursor, ovcnt, N);
    }
    {
        int cblocks = (int)(((xElems >> 2) + 255) / 256);
        fill_convert<<<FILLB + cblocks, 256, 0, stream>>>(ei, flag, cursor, colf,
                                                          ovlist, ovcnt, E, N,
                                                          x, xbf, xElems);
    }
    gather_mean<<<(N + 15) / 16, 256, 0, stream>>>(cursor, colf, ovlist, ovcnt, xbf, meanbf, N);
    sage_gemm<<<ggrid, 512, 0, stream>>>(meanbf, xbf, WcH, WgH, bl, cursor, hwbf, N, ntiles);
    gather_gcn_softmax<<<(N + 15) / 16, 256, 0, stream>>>(cursor, colf, ovlist, ovcnt, hwbf, bg, out, soft, N);
}